// Round 16
// baseline (160.274 us; speedup 1.0000x reference)
//
#include <hip/hip_runtime.h>
#include <hip/hip_bf16.h>
#include <math.h>

#define SEQ 4096
#define EDIM 768
#define NHEAD 12
#define HDIM 64
#define SE (SEQ * EDIM)
#define WMAT (EDIM * EDIM)
#define QSCALE 0.180336880111f  // 0.125 * log2(e)

typedef __attribute__((ext_vector_type(8))) __bf16 bf16x8;
typedef __attribute__((ext_vector_type(4))) float f32x4;
typedef __attribute__((ext_vector_type(8))) unsigned short u16x8;
typedef __attribute__((ext_vector_type(4))) unsigned short u16x4;
typedef unsigned short ushort_t;
typedef unsigned int uint_t;

#define MFMA16(a, b, c) __builtin_amdgcn_mfma_f32_16x16x32_bf16(a, b, c, 0, 0, 0)
#define GLOAD_LDS16(g, l)                                          \
  __builtin_amdgcn_global_load_lds(                                \
      (const __attribute__((address_space(1))) void*)(g),          \
      (__attribute__((address_space(3))) void*)(l), 16, 0, 0)

__device__ __forceinline__ unsigned short bfbits(float x) {
  return __builtin_bit_cast(unsigned short, (__bf16)x);
}
__device__ __forceinline__ void split1(float x, unsigned short* h,
                                       unsigned short* l) {
  __bf16 hb = (__bf16)x;
  *h = __builtin_bit_cast(unsigned short, hb);
  *l = __builtin_bit_cast(unsigned short, (__bf16)(x - (float)hb));
}
__device__ __forceinline__ bf16x8 ones8() {
  u16x8 u;
#pragma unroll
  for (int e = 0; e < 8; ++e) u[e] = 0x3F80;  // bf16 1.0
  return __builtin_bit_cast(bf16x8, u);
}
// bare hardware exp2: v_exp_f32 computes 2^x (1 ULP)
__device__ __forceinline__ float exp2_hw(float x) {
  float r;
  asm("v_exp_f32 %0, %1" : "=v"(r) : "v"(x));
  return r;
}

// ---------------------------------------------------------------------------
// Prep: round Wq/Wk/Wv to bf16; split Wo hi/lo; round x to bf16.
// ---------------------------------------------------------------------------
__global__ __launch_bounds__(256) void wprep_kernel(
    const float* __restrict__ W0, const float* __restrict__ W1,
    const float* __restrict__ W2, const float* __restrict__ W3,
    ushort_t* __restrict__ WB, ushort_t* __restrict__ WOH,
    ushort_t* __restrict__ WOL) {
  const int m = blockIdx.y;
  const float* src = (m == 0) ? W0 : (m == 1) ? W1 : (m == 2) ? W2 : W3;
  const size_t i = ((size_t)blockIdx.x * 256 + threadIdx.x) * 8;
  float4 a = *(const float4*)(src + i);
  float4 b = *(const float4*)(src + i + 4);
  float fv[8] = {a.x, a.y, a.z, a.w, b.x, b.y, b.z, b.w};
  if (m < 3) {
    u16x8 hh;
#pragma unroll
    for (int e = 0; e < 8; ++e) hh[e] = bfbits(fv[e]);
    *(u16x8*)(WB + (size_t)m * WMAT + i) = hh;
  } else {
    u16x8 hh, ll;
#pragma unroll
    for (int e = 0; e < 8; ++e) {
      unsigned short x, y;
      split1(fv[e], &x, &y);
      hh[e] = x;
      ll[e] = y;
    }
    *(u16x8*)(WOH + i) = hh;
    *(u16x8*)(WOL + i) = ll;
  }
}

__global__ __launch_bounds__(256) void xprep_kernel(
    const float* __restrict__ x, ushort_t* __restrict__ xb) {
  const size_t i = ((size_t)blockIdx.x * 256 + threadIdx.x) * 8;
  float4 a = *(const float4*)(x + i);
  float4 b = *(const float4*)(x + i + 4);
  float fv[8] = {a.x, a.y, a.z, a.w, b.x, b.y, b.z, b.w};
  u16x8 hh;
#pragma unroll
  for (int e = 0; e < 8; ++e) hh[e] = bfbits(fv[e]);
  *(u16x8*)(xb + i) = hh;
}

// ---------------------------------------------------------------------------
// Single-bf16 MFMA GEMM (QKV). z==2 writes V TRANSPOSED ([d][seq]) directly.
// ---------------------------------------------------------------------------
__global__ __launch_bounds__(256) void qkv_kernel(
    const ushort_t* __restrict__ XB, const ushort_t* __restrict__ WB,
    const float* __restrict__ bq, const float* __restrict__ bk,
    const float* __restrict__ bv, ushort_t* __restrict__ QB,
    ushort_t* __restrict__ KB, ushort_t* __restrict__ VT) {
  __shared__ __align__(16) ushort_t AS[128][32];
  __shared__ __align__(16) ushort_t BS[128][32];

  const int z = blockIdx.z;
  const ushort_t* Bmat = WB + (size_t)z * WMAT;
  const float* bias = (z == 0) ? bq : (z == 1) ? bk : bv;
  ushort_t* outp = (z == 0) ? QB : (z == 1) ? KB : VT;
  const float scale = (z == 0) ? QSCALE : 1.0f;

  const int t = threadIdx.x;
  const int lane = t & 63;
  const int w = t >> 6;
  const int tn = t & 15;
  const int g = (t >> 4) & 3;
  const int wr = w >> 1, wc = w & 1;
  const int m0 = blockIdx.x * 128;
  const int n0 = blockIdx.y * 128;

  f32x4 acc[4][4];
#pragma unroll
  for (int mi = 0; mi < 4; ++mi)
#pragma unroll
    for (int nj = 0; nj < 4; ++nj) acc[mi][nj] = (f32x4){0.f, 0.f, 0.f, 0.f};

  const int crow = lane >> 2;
  const int ccol = (lane & 3) * 8;

  for (int k0 = 0; k0 < EDIM; k0 += 32) {
    __syncthreads();
#pragma unroll
    for (int i = 0; i < 2; ++i) {
      const int ch = w + 4 * i;
      const int row = ch * 16 + crow;
      GLOAD_LDS16(XB + (size_t)(m0 + row) * EDIM + k0 + ccol, &AS[ch * 16][0]);
      GLOAD_LDS16(Bmat + (size_t)(n0 + row) * EDIM + k0 + ccol, &BS[ch * 16][0]);
    }
    __syncthreads();

    bf16x8 ah[4], bh[4];
#pragma unroll
    for (int mi = 0; mi < 4; ++mi)
      ah[mi] = __builtin_bit_cast(
          bf16x8, *(const u16x8*)&AS[wr * 64 + mi * 16 + tn][8 * g]);
#pragma unroll
    for (int nj = 0; nj < 4; ++nj)
      bh[nj] = __builtin_bit_cast(
          bf16x8, *(const u16x8*)&BS[wc * 64 + nj * 16 + tn][8 * g]);
#pragma unroll
    for (int mi = 0; mi < 4; ++mi)
#pragma unroll
      for (int nj = 0; nj < 4; ++nj)
        acc[mi][nj] = MFMA16(ah[mi], bh[nj], acc[mi][nj]);
  }

#pragma unroll
  for (int mi = 0; mi < 4; ++mi) {
    const int rb = m0 + wr * 64 + mi * 16 + 4 * g;
#pragma unroll
    for (int nj = 0; nj < 4; ++nj) {
      const int col = n0 + wc * 64 + nj * 16 + tn;
      const float bb = bias[col];
      if (z == 2) {
        u16x4 pk;
#pragma unroll
        for (int r = 0; r < 4; ++r) pk[r] = bfbits(acc[mi][nj][r] + bb);
        *(u16x4*)(outp + (size_t)col * SEQ + rb) = pk;  // V^T [d][seq]
      } else {
#pragma unroll
        for (int r = 0; r < 4; ++r)
          outp[(size_t)(rb + r) * EDIM + col] =
              bfbits((acc[mi][nj][r] + bb) * scale);
      }
    }
  }
}

// ---------------------------------------------------------------------------
// 3-term split MFMA GEMM (for proj): fp32-accurate, fp32 out + bias.
// ---------------------------------------------------------------------------
__global__ __launch_bounds__(256) void proj_kernel(
    const ushort_t* __restrict__ Ah, const ushort_t* __restrict__ Al,
    const ushort_t* __restrict__ Bh, const ushort_t* __restrict__ Bl,
    const float* __restrict__ bias, float* __restrict__ outf) {
  __shared__ __align__(16) ushort_t AhS[128][32];
  __shared__ __align__(16) ushort_t AlS[128][32];
  __shared__ __align__(16) ushort_t BhS[128][32];
  __shared__ __align__(16) ushort_t BlS[128][32];

  const int t = threadIdx.x;
  const int lane = t & 63;
  const int w = t >> 6;
  const int tn = t & 15;
  const int g = (t >> 4) & 3;
  const int wr = w >> 1, wc = w & 1;
  const int m0 = blockIdx.x * 128;
  const int n0 = blockIdx.y * 128;

  f32x4 acc[4][4];
#pragma unroll
  for (int mi = 0; mi < 4; ++mi)
#pragma unroll
    for (int nj = 0; nj < 4; ++nj) acc[mi][nj] = (f32x4){0.f, 0.f, 0.f, 0.f};

  const int crow = lane >> 2;
  const int ccol = (lane & 3) * 8;

  for (int k0 = 0; k0 < EDIM; k0 += 32) {
    __syncthreads();
#pragma unroll
    for (int i = 0; i < 2; ++i) {
      const int ch = w + 4 * i;
      const int row = ch * 16 + crow;
      const size_t ga = (size_t)(m0 + row) * EDIM + k0 + ccol;
      const size_t gb = (size_t)(n0 + row) * EDIM + k0 + ccol;
      GLOAD_LDS16(Ah + ga, &AhS[ch * 16][0]);
      GLOAD_LDS16(Al + ga, &AlS[ch * 16][0]);
      GLOAD_LDS16(Bh + gb, &BhS[ch * 16][0]);
      GLOAD_LDS16(Bl + gb, &BlS[ch * 16][0]);
    }
    __syncthreads();

    bf16x8 ah[4], al[4], bh[4], bl[4];
#pragma unroll
    for (int mi = 0; mi < 4; ++mi) {
      ah[mi] = __builtin_bit_cast(
          bf16x8, *(const u16x8*)&AhS[wr * 64 + mi * 16 + tn][8 * g]);
      al[mi] = __builtin_bit_cast(
          bf16x8, *(const u16x8*)&AlS[wr * 64 + mi * 16 + tn][8 * g]);
    }
#pragma unroll
    for (int nj = 0; nj < 4; ++nj) {
      bh[nj] = __builtin_bit_cast(
          bf16x8, *(const u16x8*)&BhS[wc * 64 + nj * 16 + tn][8 * g]);
      bl[nj] = __builtin_bit_cast(
          bf16x8, *(const u16x8*)&BlS[wc * 64 + nj * 16 + tn][8 * g]);
    }
#pragma unroll
    for (int mi = 0; mi < 4; ++mi)
#pragma unroll
      for (int nj = 0; nj < 4; ++nj)
        acc[mi][nj] = MFMA16(ah[mi], bh[nj], acc[mi][nj]);
#pragma unroll
    for (int mi = 0; mi < 4; ++mi)
#pragma unroll
      for (int nj = 0; nj < 4; ++nj)
        acc[mi][nj] = MFMA16(al[mi], bh[nj], acc[mi][nj]);
#pragma unroll
    for (int mi = 0; mi < 4; ++mi)
#pragma unroll
      for (int nj = 0; nj < 4; ++nj)
        acc[mi][nj] = MFMA16(ah[mi], bl[nj], acc[mi][nj]);
  }

#pragma unroll
  for (int mi = 0; mi < 4; ++mi) {
    const int rb = m0 + wr * 64 + mi * 16 + 4 * g;
#pragma unroll
    for (int nj = 0; nj < 4; ++nj) {
      const int col = n0 + wc * 64 + nj * 16 + tn;
      const float bb = bias[col];
#pragma unroll
      for (int r = 0; r < 4; ++r)
        outf[(size_t)(rb + r) * EDIM + col] = acc[mi][nj][r] + bb;
    }
  }
}

// ---------------------------------------------------------------------------
// MFMA flash attention (round-15 structure, issue-bound micro-opts):
//  - 4 waves = 2 q-halves x 2 key-halves, each 32q x 32keys per 64-key tile.
//  - T5: s_setprio(1) around MFMA clusters (arbitrate issue vs other blocks).
//  - s init via loop-invariant zero4 C-operand (no per-tile v_movs).
//  - Per-buffer LDS base pointers hoisted out of the K-loop.
//  - Verified paths: swapped QK^T, packed-b64 P, v_exp_f32, ones-MFMA
//    rowsum, XOR-swizzled gload_lds staging, LDS key-half merge epilogue.
// ---------------------------------------------------------------------------
__global__ __launch_bounds__(256) void attn_kernel(
    const ushort_t* __restrict__ QB, const ushort_t* __restrict__ KBg,
    const ushort_t* __restrict__ VTg, ushort_t* __restrict__ Ch_g,
    ushort_t* __restrict__ Cl_g) {
  __shared__ __align__(16) char SMEM[43008];
  ushort_t(*KS)[64][64] = (ushort_t(*)[64][64])SMEM;             // 16 KB
  ushort_t(*VS)[64][64] = (ushort_t(*)[64][64])(SMEM + 16384);   // 16 KB
  ushort_t(*Ps)[2][16][40] = (ushort_t(*)[2][16][40])(SMEM + 32768);  // 10 KB

  const int t = threadIdx.x;
  const int lane = t & 63;
  const int tn = t & 15;
  const int g = (t >> 4) & 3;
  const int kg = g * 8;
  const int wid = t >> 6;
  const int wq = wid & 1;   // q-half
  const int wk = wid >> 1;  // key-half
  const int h = blockIdx.y;
  const int q0 = blockIdx.x * 64;
  const int hoff = h * HDIM;

  // Q fragments: 2 q-sub-blocks x 2 d-steps (B-operand of swapped QK^T)
  bf16x8 qbf[2][2];
#pragma unroll
  for (int qb = 0; qb < 2; ++qb) {
    const ushort_t* qp =
        QB + (size_t)(q0 + 32 * wq + 16 * qb + tn) * EDIM + hoff;
    qbf[qb][0] = __builtin_bit_cast(bf16x8, *(const u16x8*)(qp + kg));
    qbf[qb][1] = __builtin_bit_cast(bf16x8, *(const u16x8*)(qp + 32 + kg));
  }

  // gload_lds staging roles; source pre-XOR-swizzled (rule #21)
  const int srow = lane >> 3;
  const int sxor = ((lane & 7) ^ srow) << 4;
  const int rswz = (tn & 7) << 4;
  const int off0 = (16 * g) ^ rswz;            // d 8g..8g+7 (bytes)
  const int off1 = (64 + 16 * g) ^ rswz;       // d 32+8g..
  const int offv = (64 * wk + 16 * g) ^ rswz;  // keys 32wk+8g.. (bytes)

  // hoisted per-buffer LDS read bases (loop-invariant)
  const char* kbase[2] = {(const char*)&KS[0][32 * wk + tn][0],
                          (const char*)&KS[1][32 * wk + tn][0]};
  const char* vbase[2] = {(const char*)&VS[0][tn][0],
                          (const char*)&VS[1][tn][0]};

  const bf16x8 ones = ones8();
  const f32x4 zero4 = (f32x4){0.f, 0.f, 0.f, 0.f};
  f32x4 o[4][2], lsum[2];
#pragma unroll
  for (int qb = 0; qb < 2; ++qb) {
    lsum[qb] = zero4;
#pragma unroll
    for (int j = 0; j < 4; ++j) o[j][qb] = zero4;
  }

  // prologue: stage tile 0 into buf 0
#pragma unroll
  for (int c = 0; c < 2; ++c) {
    const int row = 16 * wid + 8 * c + srow;
    GLOAD_LDS16((const char*)(KBg + (size_t)row * EDIM + hoff) + sxor,
                &KS[0][16 * wid + 8 * c][0]);
    GLOAD_LDS16((const char*)(VTg + (size_t)(hoff + row) * SEQ) + sxor,
                &VS[0][16 * wid + 8 * c][0]);
  }

  for (int it = 0; it < SEQ / 64; ++it) {
    const int buf = it & 1;
    __syncthreads();  // drains own DMAs + all waves done with buf^1

    if (it + 1 < SEQ / 64) {  // stage next tile into buf^1
      const int k0n = (it + 1) * 64;
#pragma unroll
      for (int c = 0; c < 2; ++c) {
        const int row = 16 * wid + 8 * c + srow;
        GLOAD_LDS16(
            (const char*)(KBg + (size_t)(k0n + row) * EDIM + hoff) + sxor,
            &KS[buf ^ 1][16 * wid + 8 * c][0]);
        GLOAD_LDS16(
            (const char*)(VTg + (size_t)(hoff + row) * SEQ + k0n) + sxor,
            &VS[buf ^ 1][16 * wid + 8 * c][0]);
      }
    }

    // S^T = K Q : s[kb][qb], keys 32wk+16kb+4g+r, q = 32wq+16qb+tn
    f32x4 s[2][2];
    __builtin_amdgcn_s_setprio(1);
#pragma unroll
    for (int kb = 0; kb < 2; ++kb) {
      const char* krow = kbase[buf] + kb * 16 * 128;  // +16 rows * 128 B
      const bf16x8 ka =
          __builtin_bit_cast(bf16x8, *(const u16x8*)(krow + off0));
      const bf16x8 kc =
          __builtin_bit_cast(bf16x8, *(const u16x8*)(krow + off1));
#pragma unroll
      for (int qb = 0; qb < 2; ++qb) {
        s[kb][qb] = MFMA16(ka, qbf[qb][0], zero4);
        s[kb][qb] = MFMA16(kc, qbf[qb][1], s[kb][qb]);
      }
    }
    __builtin_amdgcn_s_setprio(0);

    // p = 2^s ; packed P writes: Ps[wid][qb][q=tn][local key 16kb+4g..+3]
#pragma unroll
    for (int kb = 0; kb < 2; ++kb)
#pragma unroll
      for (int qb = 0; qb < 2; ++qb) {
        uint2 pk;
        pk.x = (uint_t)bfbits(exp2_hw(s[kb][qb][0])) |
               ((uint_t)bfbits(exp2_hw(s[kb][qb][1])) << 16);
        pk.y = (uint_t)bfbits(exp2_hw(s[kb][qb][2])) |
               ((uint_t)bfbits(exp2_hw(s[kb][qb][3])) << 16);
        *(uint2*)&Ps[wid][qb][tn][16 * kb + 4 * g] = pk;
      }

    // pa[qb]: A-operand P[q=tn][local keys kg..kg+7] (wave-local)
    const bf16x8 pa0 =
        __builtin_bit_cast(bf16x8, *(const u16x8*)&Ps[wid][0][tn][kg]);
    const bf16x8 pa1 =
        __builtin_bit_cast(bf16x8, *(const u16x8*)&Ps[wid][1][tn][kg]);

    // O += P V over this wave's 32 keys ; lsum += P @ ones
    __builtin_amdgcn_s_setprio(1);
#pragma unroll
    for (int j = 0; j < 4; ++j) {
      const char* vrow = vbase[buf] + j * 16 * 128;
      const bf16x8 vf =
          __builtin_bit_cast(bf16x8, *(const u16x8*)(vrow + offv));
      o[j][0] = MFMA16(pa0, vf, o[j][0]);
      o[j][1] = MFMA16(pa1, vf, o[j][1]);
    }
    lsum[0] = MFMA16(pa0, ones, lsum[0]);
    lsum[1] = MFMA16(pa1, ones, lsum[1]);
    __builtin_amdgcn_s_setprio(0);
  }

  // ---- epilogue: merge key-halves via reused LDS, normalize, store ----
  float(*Of)[68] = (float(*)[68])SMEM;       // [64 d][68 q] = 17408 B
  float* Lf = (float*)(SMEM + 17408);        // [64 q]

  __syncthreads();  // all tile compute done; SMEM reusable
  if (wk == 1) {
#pragma unroll
    for (int qb = 0; qb < 2; ++qb) {
#pragma unroll
      for (int j = 0; j < 4; ++j)
        *(float4*)&Of[16 * j + tn][32 * wq + 16 * qb + 4 * g] =
            make_float4(o[j][qb][0], o[j][qb][1], o[j][qb][2], o[j][qb][3]);
      if (tn == 0) {
#pragma unroll
        for (int r = 0; r < 4; ++r)
          Lf[32 * wq + 16 * qb + 4 * g + r] = lsum[qb][r];
      }
    }
  }
  __syncthreads();
  if (wk == 0) {
#pragma unroll
    for (int qb = 0; qb < 2; ++qb) {
      float linv[4];
#pragma unroll
      for (int r = 0; r < 4; ++r)
        linv[r] =
            1.f / (lsum[qb][r] + Lf[32 * wq + 16 * qb + 4 * g + r]);
#pragma unroll
      for (int j = 0; j < 4; ++j) {
        const float4 ov =
            *(const float4*)&Of[16 * j + tn][32 * wq + 16 * qb + 4 * g];
        const float vals[4] = {(o[j][qb][0] + ov.x) * linv[0],
                               (o[j][qb][1] + ov.y) * linv[1],
                               (o[j][qb][2] + ov.z) * linv[2],
                               (o[j][qb][3] + ov.w) * linv[3]};
#pragma unroll
        for (int r = 0; r < 4; ++r) {
          unsigned short hh, ll;
          split1(vals[r], &hh, &ll);
          const size_t idx =
              (size_t)(q0 + 32 * wq + 16 * qb + 4 * g + r) * EDIM + hoff +
              16 * j + tn;
          Ch_g[idx] = hh;
          Cl_g[idx] = ll;
        }
      }
    }
  }
}

extern "C" void kernel_launch(void* const* d_in, const int* in_sizes, int n_in,
                              void* d_out, int out_size, void* d_ws,
                              size_t ws_size, hipStream_t stream) {
  const float* x  = (const float*)d_in[0];
  const float* Wq = (const float*)d_in[1];
  const float* bq = (const float*)d_in[2];
  const float* Wk = (const float*)d_in[3];
  const float* bk = (const float*)d_in[4];
  const float* Wv = (const float*)d_in[5];
  const float* bv = (const float*)d_in[6];
  const float* Wo = (const float*)d_in[7];
  const float* bo = (const float*)d_in[8];
  float* out = (float*)d_out;

  // ws layout, u16 elements (~43.6 MB)
  ushort_t* WB  = (ushort_t*)d_ws;              // 3*WMAT (Wq,Wk,Wv bf16)
  ushort_t* WOH = WB + (size_t)3 * WMAT;        // WMAT
  ushort_t* WOL = WOH + (size_t)WMAT;           // WMAT
  ushort_t* XB  = WOL + (size_t)WMAT;           // SE
  ushort_t* QB  = XB + (size_t)SE;              // SE
  ushort_t* KB  = QB + (size_t)SE;              // SE
  ushort_t* VT  = KB + (size_t)SE;              // SE (V^T [768][4096])
  ushort_t* CH  = VT + (size_t)SE;              // SE
  ushort_t* CL  = CH + (size_t)SE;              // SE

  dim3 gw(WMAT / 2048, 4);
  wprep_kernel<<<gw, 256, 0, stream>>>(Wq, Wk, Wv, Wo, WB, WOH, WOL);
  xprep_kernel<<<SE / 2048, 256, 0, stream>>>(x, XB);

  dim3 gq(SEQ / 128, EDIM / 128, 3);
  qkv_kernel<<<gq, 256, 0, stream>>>(XB, WB, bq, bk, bv, QB, KB, VT);

  dim3 ga(SEQ / 64, NHEAD);
  attn_kernel<<<ga, 256, 0, stream>>>(QB, KB, VT, CH, CL);

  dim3 go(SEQ / 128, EDIM / 128);
  proj_kernel<<<go, 256, 0, stream>>>(CH, CL, WOH, WOL, bo, out);
}

// Round 17
// 158.509 us; speedup vs baseline: 1.0111x; 1.0111x over previous
//
#include <hip/hip_runtime.h>
#include <hip/hip_bf16.h>
#include <math.h>

#define SEQ 4096
#define EDIM 768
#define NHEAD 12
#define HDIM 64
#define SE (SEQ * EDIM)
#define WMAT (EDIM * EDIM)
#define QSCALE 0.180336880111f  // 0.125 * log2(e)

typedef __attribute__((ext_vector_type(8))) __bf16 bf16x8;
typedef __attribute__((ext_vector_type(4))) float f32x4;
typedef __attribute__((ext_vector_type(8))) unsigned short u16x8;
typedef __attribute__((ext_vector_type(4))) unsigned short u16x4;
typedef unsigned short ushort_t;
typedef unsigned int uint_t;

#define MFMA16(a, b, c) __builtin_amdgcn_mfma_f32_16x16x32_bf16(a, b, c, 0, 0, 0)
#define GLOAD_LDS16(g, l)                                          \
  __builtin_amdgcn_global_load_lds(                                \
      (const __attribute__((address_space(1))) void*)(g),          \
      (__attribute__((address_space(3))) void*)(l), 16, 0, 0)

__device__ __forceinline__ unsigned short bfbits(float x) {
  return __builtin_bit_cast(unsigned short, (__bf16)x);
}
__device__ __forceinline__ void split1(float x, unsigned short* h,
                                       unsigned short* l) {
  __bf16 hb = (__bf16)x;
  *h = __builtin_bit_cast(unsigned short, hb);
  *l = __builtin_bit_cast(unsigned short, (__bf16)(x - (float)hb));
}
__device__ __forceinline__ bf16x8 ones8() {
  u16x8 u;
#pragma unroll
  for (int e = 0; e < 8; ++e) u[e] = 0x3F80;  // bf16 1.0
  return __builtin_bit_cast(bf16x8, u);
}
// bare hardware exp2: v_exp_f32 computes 2^x (1 ULP)
__device__ __forceinline__ float exp2_hw(float x) {
  float r;
  asm("v_exp_f32 %0, %1" : "=v"(r) : "v"(x));
  return r;
}

// ---------------------------------------------------------------------------
// Prep: round Wq/Wk/Wv to bf16; split Wo hi/lo; round x to bf16.
// ---------------------------------------------------------------------------
__global__ __launch_bounds__(256) void wprep_kernel(
    const float* __restrict__ W0, const float* __restrict__ W1,
    const float* __restrict__ W2, const float* __restrict__ W3,
    ushort_t* __restrict__ WB, ushort_t* __restrict__ WOH,
    ushort_t* __restrict__ WOL) {
  const int m = blockIdx.y;
  const float* src = (m == 0) ? W0 : (m == 1) ? W1 : (m == 2) ? W2 : W3;
  const size_t i = ((size_t)blockIdx.x * 256 + threadIdx.x) * 8;
  float4 a = *(const float4*)(src + i);
  float4 b = *(const float4*)(src + i + 4);
  float fv[8] = {a.x, a.y, a.z, a.w, b.x, b.y, b.z, b.w};
  if (m < 3) {
    u16x8 hh;
#pragma unroll
    for (int e = 0; e < 8; ++e) hh[e] = bfbits(fv[e]);
    *(u16x8*)(WB + (size_t)m * WMAT + i) = hh;
  } else {
    u16x8 hh, ll;
#pragma unroll
    for (int e = 0; e < 8; ++e) {
      unsigned short x, y;
      split1(fv[e], &x, &y);
      hh[e] = x;
      ll[e] = y;
    }
    *(u16x8*)(WOH + i) = hh;
    *(u16x8*)(WOL + i) = ll;
  }
}

__global__ __launch_bounds__(256) void xprep_kernel(
    const float* __restrict__ x, ushort_t* __restrict__ xb) {
  const size_t i = ((size_t)blockIdx.x * 256 + threadIdx.x) * 8;
  float4 a = *(const float4*)(x + i);
  float4 b = *(const float4*)(x + i + 4);
  float fv[8] = {a.x, a.y, a.z, a.w, b.x, b.y, b.z, b.w};
  u16x8 hh;
#pragma unroll
  for (int e = 0; e < 8; ++e) hh[e] = bfbits(fv[e]);
  *(u16x8*)(xb + i) = hh;
}

// ---------------------------------------------------------------------------
// Single-bf16 MFMA GEMM (QKV). z==2 writes V TRANSPOSED ([d][seq]) directly.
// ---------------------------------------------------------------------------
__global__ __launch_bounds__(256) void qkv_kernel(
    const ushort_t* __restrict__ XB, const ushort_t* __restrict__ WB,
    const float* __restrict__ bq, const float* __restrict__ bk,
    const float* __restrict__ bv, ushort_t* __restrict__ QB,
    ushort_t* __restrict__ KB, ushort_t* __restrict__ VT) {
  __shared__ __align__(16) ushort_t AS[128][32];
  __shared__ __align__(16) ushort_t BS[128][32];

  const int z = blockIdx.z;
  const ushort_t* Bmat = WB + (size_t)z * WMAT;
  const float* bias = (z == 0) ? bq : (z == 1) ? bk : bv;
  ushort_t* outp = (z == 0) ? QB : (z == 1) ? KB : VT;
  const float scale = (z == 0) ? QSCALE : 1.0f;

  const int t = threadIdx.x;
  const int lane = t & 63;
  const int w = t >> 6;
  const int tn = t & 15;
  const int g = (t >> 4) & 3;
  const int wr = w >> 1, wc = w & 1;
  const int m0 = blockIdx.x * 128;
  const int n0 = blockIdx.y * 128;

  f32x4 acc[4][4];
#pragma unroll
  for (int mi = 0; mi < 4; ++mi)
#pragma unroll
    for (int nj = 0; nj < 4; ++nj) acc[mi][nj] = (f32x4){0.f, 0.f, 0.f, 0.f};

  const int crow = lane >> 2;
  const int ccol = (lane & 3) * 8;

  for (int k0 = 0; k0 < EDIM; k0 += 32) {
    __syncthreads();
#pragma unroll
    for (int i = 0; i < 2; ++i) {
      const int ch = w + 4 * i;
      const int row = ch * 16 + crow;
      GLOAD_LDS16(XB + (size_t)(m0 + row) * EDIM + k0 + ccol, &AS[ch * 16][0]);
      GLOAD_LDS16(Bmat + (size_t)(n0 + row) * EDIM + k0 + ccol, &BS[ch * 16][0]);
    }
    __syncthreads();

    bf16x8 ah[4], bh[4];
#pragma unroll
    for (int mi = 0; mi < 4; ++mi)
      ah[mi] = __builtin_bit_cast(
          bf16x8, *(const u16x8*)&AS[wr * 64 + mi * 16 + tn][8 * g]);
#pragma unroll
    for (int nj = 0; nj < 4; ++nj)
      bh[nj] = __builtin_bit_cast(
          bf16x8, *(const u16x8*)&BS[wc * 64 + nj * 16 + tn][8 * g]);
#pragma unroll
    for (int mi = 0; mi < 4; ++mi)
#pragma unroll
      for (int nj = 0; nj < 4; ++nj)
        acc[mi][nj] = MFMA16(ah[mi], bh[nj], acc[mi][nj]);
  }

#pragma unroll
  for (int mi = 0; mi < 4; ++mi) {
    const int rb = m0 + wr * 64 + mi * 16 + 4 * g;
#pragma unroll
    for (int nj = 0; nj < 4; ++nj) {
      const int col = n0 + wc * 64 + nj * 16 + tn;
      const float bb = bias[col];
      if (z == 2) {
        u16x4 pk;
#pragma unroll
        for (int r = 0; r < 4; ++r) pk[r] = bfbits(acc[mi][nj][r] + bb);
        *(u16x4*)(outp + (size_t)col * SEQ + rb) = pk;  // V^T [d][seq]
      } else {
#pragma unroll
        for (int r = 0; r < 4; ++r)
          outp[(size_t)(rb + r) * EDIM + col] =
              bfbits((acc[mi][nj][r] + bb) * scale);
      }
    }
  }
}

// ---------------------------------------------------------------------------
// 3-term split MFMA GEMM (for proj): fp32-accurate, fp32 out + bias.
// ---------------------------------------------------------------------------
__global__ __launch_bounds__(256) void proj_kernel(
    const ushort_t* __restrict__ Ah, const ushort_t* __restrict__ Al,
    const ushort_t* __restrict__ Bh, const ushort_t* __restrict__ Bl,
    const float* __restrict__ bias, float* __restrict__ outf) {
  __shared__ __align__(16) ushort_t AhS[128][32];
  __shared__ __align__(16) ushort_t AlS[128][32];
  __shared__ __align__(16) ushort_t BhS[128][32];
  __shared__ __align__(16) ushort_t BlS[128][32];

  const int t = threadIdx.x;
  const int lane = t & 63;
  const int w = t >> 6;
  const int tn = t & 15;
  const int g = (t >> 4) & 3;
  const int wr = w >> 1, wc = w & 1;
  const int m0 = blockIdx.x * 128;
  const int n0 = blockIdx.y * 128;

  f32x4 acc[4][4];
#pragma unroll
  for (int mi = 0; mi < 4; ++mi)
#pragma unroll
    for (int nj = 0; nj < 4; ++nj) acc[mi][nj] = (f32x4){0.f, 0.f, 0.f, 0.f};

  const int crow = lane >> 2;
  const int ccol = (lane & 3) * 8;

  for (int k0 = 0; k0 < EDIM; k0 += 32) {
    __syncthreads();
#pragma unroll
    for (int i = 0; i < 2; ++i) {
      const int ch = w + 4 * i;
      const int row = ch * 16 + crow;
      const size_t ga = (size_t)(m0 + row) * EDIM + k0 + ccol;
      const size_t gb = (size_t)(n0 + row) * EDIM + k0 + ccol;
      GLOAD_LDS16(Ah + ga, &AhS[ch * 16][0]);
      GLOAD_LDS16(Al + ga, &AlS[ch * 16][0]);
      GLOAD_LDS16(Bh + gb, &BhS[ch * 16][0]);
      GLOAD_LDS16(Bl + gb, &BlS[ch * 16][0]);
    }
    __syncthreads();

    bf16x8 ah[4], al[4], bh[4], bl[4];
#pragma unroll
    for (int mi = 0; mi < 4; ++mi) {
      ah[mi] = __builtin_bit_cast(
          bf16x8, *(const u16x8*)&AhS[wr * 64 + mi * 16 + tn][8 * g]);
      al[mi] = __builtin_bit_cast(
          bf16x8, *(const u16x8*)&AlS[wr * 64 + mi * 16 + tn][8 * g]);
    }
#pragma unroll
    for (int nj = 0; nj < 4; ++nj) {
      bh[nj] = __builtin_bit_cast(
          bf16x8, *(const u16x8*)&BhS[wc * 64 + nj * 16 + tn][8 * g]);
      bl[nj] = __builtin_bit_cast(
          bf16x8, *(const u16x8*)&BlS[wc * 64 + nj * 16 + tn][8 * g]);
    }
#pragma unroll
    for (int mi = 0; mi < 4; ++mi)
#pragma unroll
      for (int nj = 0; nj < 4; ++nj)
        acc[mi][nj] = MFMA16(ah[mi], bh[nj], acc[mi][nj]);
#pragma unroll
    for (int mi = 0; mi < 4; ++mi)
#pragma unroll
      for (int nj = 0; nj < 4; ++nj)
        acc[mi][nj] = MFMA16(al[mi], bh[nj], acc[mi][nj]);
#pragma unroll
    for (int mi = 0; mi < 4; ++mi)
#pragma unroll
      for (int nj = 0; nj < 4; ++nj)
        acc[mi][nj] = MFMA16(ah[mi], bl[nj], acc[mi][nj]);
  }

#pragma unroll
  for (int mi = 0; mi < 4; ++mi) {
    const int rb = m0 + wr * 64 + mi * 16 + 4 * g;
#pragma unroll
    for (int nj = 0; nj < 4; ++nj) {
      const int col = n0 + wc * 64 + nj * 16 + tn;
      const float bb = bias[col];
#pragma unroll
      for (int r = 0; r < 4; ++r)
        outf[(size_t)(rb + r) * EDIM + col] = acc[mi][nj][r] + bb;
    }
  }
}

// ---------------------------------------------------------------------------
// MFMA flash attention (round-15 body verbatim) + T1 XCD-aware block
// swizzle: grid is 768 = 8 * 96 blocks launched 1-D; remap o=(b&7)*96+b>>3
// so each XCD serves 96 consecutive (qtile,head) ids = <=2 heads -> that
// head's K/V stays resident in the XCD's 4MB L2 (was: all 12 heads touched
// by every XCD, 3x K/V over-fetch at 900cy HBM-miss latency).
//  - 4 waves = 2 q-halves x 2 key-halves, each 32q x 32keys per 64-key tile.
//  - Swapped QK^T, packed-b64 P, v_exp_f32, ones-MFMA rowsum, XOR-swizzled
//    gload_lds staging, LDS key-half merge epilogue (all verified).
// ---------------------------------------------------------------------------
__global__ __launch_bounds__(256) void attn_kernel(
    const ushort_t* __restrict__ QB, const ushort_t* __restrict__ KBg,
    const ushort_t* __restrict__ VTg, ushort_t* __restrict__ Ch_g,
    ushort_t* __restrict__ Cl_g) {
  __shared__ __align__(16) char SMEM[43008];
  ushort_t(*KS)[64][64] = (ushort_t(*)[64][64])SMEM;             // 16 KB
  ushort_t(*VS)[64][64] = (ushort_t(*)[64][64])(SMEM + 16384);   // 16 KB
  ushort_t(*Ps)[2][16][40] = (ushort_t(*)[2][16][40])(SMEM + 32768);  // 10 KB

  const int t = threadIdx.x;
  const int lane = t & 63;
  const int tn = t & 15;
  const int g = (t >> 4) & 3;
  const int kg = g * 8;
  const int wid = t >> 6;
  const int wq = wid & 1;   // q-half
  const int wk = wid >> 1;  // key-half
  // T1 XCD swizzle: 768 blocks = 8 XCDs x 96; consecutive o share a head
  const int b = blockIdx.x;
  const int o = (b & 7) * 96 + (b >> 3);
  const int h = o >> 6;          // head 0..11
  const int q0 = (o & 63) * 64;  // q-tile
  const int hoff = h * HDIM;

  // Q fragments: 2 q-sub-blocks x 2 d-steps (B-operand of swapped QK^T)
  bf16x8 qbf[2][2];
#pragma unroll
  for (int qb = 0; qb < 2; ++qb) {
    const ushort_t* qp =
        QB + (size_t)(q0 + 32 * wq + 16 * qb + tn) * EDIM + hoff;
    qbf[qb][0] = __builtin_bit_cast(bf16x8, *(const u16x8*)(qp + kg));
    qbf[qb][1] = __builtin_bit_cast(bf16x8, *(const u16x8*)(qp + 32 + kg));
  }

  // gload_lds staging roles (identical to round 9); source pre-XOR-swizzled
  const int srow = lane >> 3;
  const int sxor = ((lane & 7) ^ srow) << 4;
  const int rswz = (tn & 7) << 4;
  const int off0 = (16 * g) ^ rswz;            // d 8g..8g+7 (bytes)
  const int off1 = (64 + 16 * g) ^ rswz;       // d 32+8g..
  const int offv = (64 * wk + 16 * g) ^ rswz;  // keys 32wk+8g.. (bytes)

  const bf16x8 ones = ones8();
  f32x4 o_[4][2], lsum[2];
#pragma unroll
  for (int qb = 0; qb < 2; ++qb) {
    lsum[qb] = (f32x4){0.f, 0.f, 0.f, 0.f};
#pragma unroll
    for (int j = 0; j < 4; ++j) o_[j][qb] = (f32x4){0.f, 0.f, 0.f, 0.f};
  }

  // prologue: stage tile 0 into buf 0
#pragma unroll
  for (int c = 0; c < 2; ++c) {
    const int row = 16 * wid + 8 * c + srow;
    GLOAD_LDS16((const char*)(KBg + (size_t)row * EDIM + hoff) + sxor,
                &KS[0][16 * wid + 8 * c][0]);
    GLOAD_LDS16((const char*)(VTg + (size_t)(hoff + row) * SEQ) + sxor,
                &VS[0][16 * wid + 8 * c][0]);
  }

  for (int it = 0; it < SEQ / 64; ++it) {
    const int buf = it & 1;
    __syncthreads();  // drains own DMAs + all waves done with buf^1

    if (it + 1 < SEQ / 64) {  // stage next tile into buf^1
      const int k0n = (it + 1) * 64;
#pragma unroll
      for (int c = 0; c < 2; ++c) {
        const int row = 16 * wid + 8 * c + srow;
        GLOAD_LDS16(
            (const char*)(KBg + (size_t)(k0n + row) * EDIM + hoff) + sxor,
            &KS[buf ^ 1][16 * wid + 8 * c][0]);
        GLOAD_LDS16(
            (const char*)(VTg + (size_t)(hoff + row) * SEQ + k0n) + sxor,
            &VS[buf ^ 1][16 * wid + 8 * c][0]);
      }
    }

    // S^T = K Q : s[kb][qb], keys 32wk+16kb+4g+r, q = 32wq+16qb+tn
    f32x4 s[2][2];
#pragma unroll
    for (int kb = 0; kb < 2; ++kb) {
      const char* krow = (const char*)&KS[buf][32 * wk + 16 * kb + tn][0];
      const bf16x8 ka =
          __builtin_bit_cast(bf16x8, *(const u16x8*)(krow + off0));
      const bf16x8 kc =
          __builtin_bit_cast(bf16x8, *(const u16x8*)(krow + off1));
#pragma unroll
      for (int qb = 0; qb < 2; ++qb) {
        s[kb][qb] = (f32x4){0.f, 0.f, 0.f, 0.f};
        s[kb][qb] = MFMA16(ka, qbf[qb][0], s[kb][qb]);
        s[kb][qb] = MFMA16(kc, qbf[qb][1], s[kb][qb]);
      }
    }

    // p = 2^s ; packed P writes: Ps[wid][qb][q=tn][local key 16kb+4g..+3]
#pragma unroll
    for (int kb = 0; kb < 2; ++kb)
#pragma unroll
      for (int qb = 0; qb < 2; ++qb) {
        uint2 pk;
        pk.x = (uint_t)bfbits(exp2_hw(s[kb][qb][0])) |
               ((uint_t)bfbits(exp2_hw(s[kb][qb][1])) << 16);
        pk.y = (uint_t)bfbits(exp2_hw(s[kb][qb][2])) |
               ((uint_t)bfbits(exp2_hw(s[kb][qb][3])) << 16);
        *(uint2*)&Ps[wid][qb][tn][16 * kb + 4 * g] = pk;
      }

    // pa[qb]: A-operand P[q=tn][local keys kg..kg+7] (wave-local)
    const bf16x8 pa0 =
        __builtin_bit_cast(bf16x8, *(const u16x8*)&Ps[wid][0][tn][kg]);
    const bf16x8 pa1 =
        __builtin_bit_cast(bf16x8, *(const u16x8*)&Ps[wid][1][tn][kg]);

    // O += P V over this wave's 32 keys ; lsum += P @ ones
#pragma unroll
    for (int j = 0; j < 4; ++j) {
      const char* vrow = (const char*)&VS[buf][16 * j + tn][0];
      const bf16x8 vf =
          __builtin_bit_cast(bf16x8, *(const u16x8*)(vrow + offv));
      o_[j][0] = MFMA16(pa0, vf, o_[j][0]);
      o_[j][1] = MFMA16(pa1, vf, o_[j][1]);
    }
    lsum[0] = MFMA16(pa0, ones, lsum[0]);
    lsum[1] = MFMA16(pa1, ones, lsum[1]);
  }

  // ---- epilogue: merge key-halves via reused LDS, normalize, store ----
  float(*Of)[68] = (float(*)[68])SMEM;       // [64 d][68 q] = 17408 B
  float* Lf = (float*)(SMEM + 17408);        // [64 q]

  __syncthreads();  // all tile compute done; SMEM reusable
  if (wk == 1) {
#pragma unroll
    for (int qb = 0; qb < 2; ++qb) {
#pragma unroll
      for (int j = 0; j < 4; ++j)
        *(float4*)&Of[16 * j + tn][32 * wq + 16 * qb + 4 * g] = make_float4(
            o_[j][qb][0], o_[j][qb][1], o_[j][qb][2], o_[j][qb][3]);
      if (tn == 0) {
#pragma unroll
        for (int r = 0; r < 4; ++r)
          Lf[32 * wq + 16 * qb + 4 * g + r] = lsum[qb][r];
      }
    }
  }
  __syncthreads();
  if (wk == 0) {
#pragma unroll
    for (int qb = 0; qb < 2; ++qb) {
      float linv[4];
#pragma unroll
      for (int r = 0; r < 4; ++r)
        linv[r] =
            1.f / (lsum[qb][r] + Lf[32 * wq + 16 * qb + 4 * g + r]);
#pragma unroll
      for (int j = 0; j < 4; ++j) {
        const float4 ov =
            *(const float4*)&Of[16 * j + tn][32 * wq + 16 * qb + 4 * g];
        const float vals[4] = {(o_[j][qb][0] + ov.x) * linv[0],
                               (o_[j][qb][1] + ov.y) * linv[1],
                               (o_[j][qb][2] + ov.z) * linv[2],
                               (o_[j][qb][3] + ov.w) * linv[3]};
#pragma unroll
        for (int r = 0; r < 4; ++r) {
          unsigned short hh, ll;
          split1(vals[r], &hh, &ll);
          const size_t idx =
              (size_t)(q0 + 32 * wq + 16 * qb + 4 * g + r) * EDIM + hoff +
              16 * j + tn;
          Ch_g[idx] = hh;
          Cl_g[idx] = ll;
        }
      }
    }
  }
}

extern "C" void kernel_launch(void* const* d_in, const int* in_sizes, int n_in,
                              void* d_out, int out_size, void* d_ws,
                              size_t ws_size, hipStream_t stream) {
  const float* x  = (const float*)d_in[0];
  const float* Wq = (const float*)d_in[1];
  const float* bq = (const float*)d_in[2];
  const float* Wk = (const float*)d_in[3];
  const float* bk = (const float*)d_in[4];
  const float* Wv = (const float*)d_in[5];
  const float* bv = (const float*)d_in[6];
  const float* Wo = (const float*)d_in[7];
  const float* bo = (const float*)d_in[8];
  float* out = (float*)d_out;

  // ws layout, u16 elements (~43.6 MB)
  ushort_t* WB  = (ushort_t*)d_ws;              // 3*WMAT (Wq,Wk,Wv bf16)
  ushort_t* WOH = WB + (size_t)3 * WMAT;        // WMAT
  ushort_t* WOL = WOH + (size_t)WMAT;           // WMAT
  ushort_t* XB  = WOL + (size_t)WMAT;           // SE
  ushort_t* QB  = XB + (size_t)SE;              // SE
  ushort_t* KB  = QB + (size_t)SE;              // SE
  ushort_t* VT  = KB + (size_t)SE;              // SE (V^T [768][4096])
  ushort_t* CH  = VT + (size_t)SE;              // SE
  ushort_t* CL  = CH + (size_t)SE;              // SE

  dim3 gw(WMAT / 2048, 4);
  wprep_kernel<<<gw, 256, 0, stream>>>(Wq, Wk, Wv, Wo, WB, WOH, WOL);
  xprep_kernel<<<SE / 2048, 256, 0, stream>>>(x, XB);

  dim3 gq(SEQ / 128, EDIM / 128, 3);
  qkv_kernel<<<gq, 256, 0, stream>>>(XB, WB, bq, bk, bv, QB, KB, VT);

  attn_kernel<<<(SEQ / 64) * NHEAD, 256, 0, stream>>>(QB, KB, VT, CH, CL);

  dim3 go(SEQ / 128, EDIM / 128);
  proj_kernel<<<go, 256, 0, stream>>>(CH, CL, WOH, WOL, bo, out);
}